// Round 18
// baseline (143.015 us; speedup 1.0000x reference)
//
#include <hip/hip_runtime.h>

// ---------------------------------------------------------------------------
// T5 cross-attention fused pipeline for MI355X (gfx950)  — round 18
// B=2, Q=KV=2048, D_MODEL=1024, H=16, D=64
// attn: 128-thr blocks (2 waves x 32q), KVBLK=64, 32KB LDS -> 4 independent
// blocks/CU (grid 1024) for cross-block pipe overlap. Same per-lane math as
// round 14's proven 32x32 core. GEMMs/prep unchanged from round 17.
// ---------------------------------------------------------------------------

typedef __attribute__((ext_vector_type(8)))  short s16x8;   // 8 bf16 (A/B frag)
typedef __attribute__((ext_vector_type(4)))  float f32x4;
typedef __attribute__((ext_vector_type(16))) float f32x16;  // 32x32 C/D frag
typedef __attribute__((ext_vector_type(4)))  int   i32x4;

#define LOG2E 1.4426950408889634f
#define EXP2(x) __builtin_amdgcn_exp2f(x)

__device__ __forceinline__ unsigned short f2bf(float f) {
  unsigned int u = __builtin_bit_cast(unsigned int, f);
  return (unsigned short)((u + 0x7FFFu + ((u >> 16) & 1u)) >> 16);  // RNE
}

__device__ __forceinline__ unsigned cvtpk(float lo, float hi) {
  unsigned r;
  asm("v_cvt_pk_bf16_f32 %0, %1, %2" : "=v"(r) : "v"(lo), "v"(hi));
  return r;
}

__device__ __forceinline__ float f3max(float a, float b, float c) {
  return fmaxf(fmaxf(a, b), c);  // clang fuses to v_max3_f32
}

__device__ __forceinline__ void gload16(const void* g, void* l) {
  __builtin_amdgcn_global_load_lds(
      (const __attribute__((address_space(1))) unsigned int*)g,
      (__attribute__((address_space(3))) unsigned int*)l, 16, 0, 0);
}

// ---------------------------------------------------------------------------
// Transpose-cast x4 in one dispatch: out[n][k] = bf16(in[k][n]), 1024x1024
// ---------------------------------------------------------------------------
__global__ __launch_bounds__(256) void k_transpose4(
    const float* __restrict__ a0, const float* __restrict__ a1,
    const float* __restrict__ a2, const float* __restrict__ a3,
    unsigned short* __restrict__ o0, unsigned short* __restrict__ o1,
    unsigned short* __restrict__ o2, unsigned short* __restrict__ o3) {
  int z = blockIdx.z;
  const float* in = (z == 0) ? a0 : (z == 1) ? a1 : (z == 2) ? a2 : a3;
  unsigned short* out = (z == 0) ? o0 : (z == 1) ? o1 : (z == 2) ? o2 : o3;
  __shared__ float tile[64][65];
  int t = threadIdx.x;
  int tx = t & 15, ty = t >> 4;
  int r0 = blockIdx.y * 64, c0 = blockIdx.x * 64;
#pragma unroll
  for (int p = 0; p < 4; ++p) {
    int r = p * 16 + ty;
    float4 v = *reinterpret_cast<const float4*>(in + (size_t)(r0 + r) * 1024 + c0 + tx * 4);
    tile[r][tx * 4 + 0] = v.x; tile[r][tx * 4 + 1] = v.y;
    tile[r][tx * 4 + 2] = v.z; tile[r][tx * 4 + 3] = v.w;
  }
  __syncthreads();
#pragma unroll
  for (int p = 0; p < 4; ++p) {
    int c = p * 16 + ty;
    unsigned int lo = (unsigned int)f2bf(tile[tx * 4 + 0][c]) |
                      ((unsigned int)f2bf(tile[tx * 4 + 1][c]) << 16);
    unsigned int hi = (unsigned int)f2bf(tile[tx * 4 + 2][c]) |
                      ((unsigned int)f2bf(tile[tx * 4 + 3][c]) << 16);
    uint2 pk2; pk2.x = lo; pk2.y = hi;
    *reinterpret_cast<uint2*>(out + (size_t)(c0 + c) * 1024 + r0 + tx * 4) = pk2;
  }
}

// ---------------------------------------------------------------------------
// Fused prep: blocks [0,4096) = RMSNorm rows (x log2e, feeds Q only);
// blocks [4096,5120) = f32->bf16 cast of key_value_states (grid-stride).
// ---------------------------------------------------------------------------
__global__ __launch_bounds__(256) void k_prep(
    const float* __restrict__ hs, const float* __restrict__ w,
    unsigned short* __restrict__ normed,
    const float* __restrict__ kvs, unsigned short* __restrict__ kvb) {
  int t = threadIdx.x;
  if (blockIdx.x < 4096) {
    int row = blockIdx.x;
    float4 v = *reinterpret_cast<const float4*>(hs + (size_t)row * 1024 + t * 4);
    float s = v.x * v.x + v.y * v.y + v.z * v.z + v.w * v.w;
#pragma unroll
    for (int m = 1; m < 64; m <<= 1) s += __shfl_xor(s, m);
    __shared__ float ps[4];
    if ((t & 63) == 0) ps[t >> 6] = s;
    __syncthreads();
    float tot = ps[0] + ps[1] + ps[2] + ps[3];
    float sc = rsqrtf(tot * (1.0f / 1024.0f) + 1e-6f) * LOG2E;
    float4 wv = *reinterpret_cast<const float4*>(w + t * 4);
    unsigned int lo = (unsigned int)f2bf(v.x * sc * wv.x) |
                      ((unsigned int)f2bf(v.y * sc * wv.y) << 16);
    unsigned int hi = (unsigned int)f2bf(v.z * sc * wv.z) |
                      ((unsigned int)f2bf(v.w * sc * wv.w) << 16);
    uint2 pk2; pk2.x = lo; pk2.y = hi;
    *reinterpret_cast<uint2*>(normed + (size_t)row * 1024 + t * 4) = pk2;
  } else {
    int i = (blockIdx.x - 4096) * 256 + t;
    for (; i < 1048576; i += 1024 * 256) {
      float4 v = *reinterpret_cast<const float4*>(kvs + (size_t)i * 4);
      unsigned int lo = (unsigned int)f2bf(v.x) | ((unsigned int)f2bf(v.y) << 16);
      unsigned int hi = (unsigned int)f2bf(v.z) | ((unsigned int)f2bf(v.w) << 16);
      uint2 pk2; pk2.x = lo; pk2.y = hi;
      *reinterpret_cast<uint2*>(kvb + (size_t)i * 4) = pk2;
    }
  }
}

// ---------------------------------------------------------------------------
// GEMM body (round-17 proven): C[M,N] = A[M,K] * Bt[N,K]^T
// BK=32 (64B rows), 32KB LDS, counted-vmcnt 2-deep pipeline.
// mode 0: bf16 out; mode 1: bf16 out transposed to vT [b][h][d][2048];
// mode 2: f32 out + residual
// ---------------------------------------------------------------------------
template <int BM>
__device__ __forceinline__ void gemm_body(
    const unsigned short* __restrict__ A, const unsigned short* __restrict__ Bt,
    void* __restrict__ Cout, const float* __restrict__ resid, int mode) {
  constexpr int MF = BM / 32;              // m-frags per wave
  constexpr int AROUNDS = BM / 64;         // gload rounds per A stage (2 or 1)
  constexpr int ATILE = BM * 64;           // bytes per A buffer (8K or 4K)
  constexpr int LPS = AROUNDS + 2;         // gloads per stage (4 or 3)
  __shared__ __align__(16) char sm[2 * ATILE + 16384];
  int t = threadIdx.x;
  int bn = blockIdx.x, bm = blockIdx.y;
  int m0 = bm * BM, n0 = bn * 128;
  int lane = t & 63, w = t >> 6, lr = lane & 15, lg = lane >> 4;
  int wr = w >> 1, wc = w & 1;

  f32x4 acc[MF][4] = {};

  const char* aA = (const char*)A + ((size_t)(m0 + (t >> 2)) * 1024 + (t & 3) * 8) * 2;
  const char* aB = (const char*)Bt + ((size_t)(n0 + (t >> 2)) * 1024 + (t & 3) * 8) * 2;

  auto stage = [&](int buf, int kt) {
    int koff = kt * 64;  // bytes into the K dimension
    char* As = sm + buf * ATILE;
    char* Bs = sm + 2 * ATILE + buf * 8192;
#pragma unroll
    for (int c = 0; c < AROUNDS; ++c)
      gload16(aA + (size_t)c * 131072 + koff, As + c * 4096 + t * 16);
#pragma unroll
    for (int c = 0; c < 2; ++c)
      gload16(aB + (size_t)c * 131072 + koff, Bs + c * 4096 + t * 16);
  };

  stage(0, 0);
  stage(1, 1);
  for (int kt = 0; kt < 32; ++kt) {
    if (kt < 31) {
      asm volatile("s_waitcnt vmcnt(%0)" :: "i"(LPS) : "memory");
    } else {
      asm volatile("s_waitcnt vmcnt(0)" ::: "memory");
    }
    __builtin_amdgcn_s_barrier();
    __builtin_amdgcn_sched_barrier(0);

    const char* As = sm + (kt & 1) * ATILE;
    const char* Bs = sm + 2 * ATILE + (kt & 1) * 8192;
    s16x8 af[MF], bfr[4];
#pragma unroll
    for (int m = 0; m < MF; ++m)
      af[m] = *reinterpret_cast<const s16x8*>(
          As + (wr * (BM / 2) + m * 16 + lr) * 64 + lg * 16);
#pragma unroll
    for (int n = 0; n < 4; ++n)
      bfr[n] = *reinterpret_cast<const s16x8*>(
          Bs + (wc * 64 + n * 16 + lr) * 64 + lg * 16);
    __builtin_amdgcn_s_setprio(1);
#pragma unroll
    for (int m = 0; m < MF; ++m)
#pragma unroll
      for (int n = 0; n < 4; ++n)
        acc[m][n] = __builtin_amdgcn_mfma_f32_16x16x32_bf16(af[m], bfr[n], acc[m][n], 0, 0, 0);
    __builtin_amdgcn_s_setprio(0);

    __builtin_amdgcn_s_barrier();
    __builtin_amdgcn_sched_barrier(0);
    if (kt < 30) stage(kt & 1, kt + 2);
  }

#pragma unroll
  for (int m = 0; m < MF; ++m)
#pragma unroll
    for (int n = 0; n < 4; ++n) {
      int colg = n0 + wc * 64 + n * 16 + lr;
      int rowb = m0 + wr * (BM / 2) + m * 16 + lg * 4;
      if (mode == 0) {
        unsigned short* C = (unsigned short*)Cout;
#pragma unroll
        for (int r = 0; r < 4; ++r)
          C[(size_t)(rowb + r) * 1024 + colg] = f2bf(acc[m][n][r]);
      } else if (mode == 1) {
        int h = colg >> 6, d = colg & 63;
        int b = rowb >> 11, kv = rowb & 2047;
        unsigned short* C = (unsigned short*)Cout +
            ((size_t)((b * 16 + h) * 64 + d) * 2048 + kv);
        unsigned int lo = (unsigned int)f2bf(acc[m][n][0]) |
                          ((unsigned int)f2bf(acc[m][n][1]) << 16);
        unsigned int hi = (unsigned int)f2bf(acc[m][n][2]) |
                          ((unsigned int)f2bf(acc[m][n][3]) << 16);
        uint2 pk2; pk2.x = lo; pk2.y = hi;
        *reinterpret_cast<uint2*>(C) = pk2;
      } else {
        float* C = (float*)Cout;
#pragma unroll
        for (int r = 0; r < 4; ++r) {
          size_t idx = (size_t)(rowb + r) * 1024 + colg;
          C[idx] = resid[idx] + acc[m][n][r];
        }
      }
    }
}

__global__ __launch_bounds__(256, 4) void k_gemm_qkv(
    const unsigned short* __restrict__ normed, const unsigned short* __restrict__ kvb,
    const unsigned short* __restrict__ wqT, const unsigned short* __restrict__ wkT,
    const unsigned short* __restrict__ wvT,
    unsigned short* __restrict__ qb, unsigned short* __restrict__ kb,
    unsigned short* __restrict__ vTb) {
  int z = blockIdx.z;
  const unsigned short* A = (z == 0) ? normed : kvb;
  const unsigned short* B = (z == 0) ? wqT : (z == 1) ? wkT : wvT;
  void* C = (z == 0) ? (void*)qb : (z == 1) ? (void*)kb : (void*)vTb;
  gemm_body<128>(A, B, C, nullptr, (z == 2) ? 1 : 0);
}

__global__ __launch_bounds__(256, 4) void k_gemm_o(
    const unsigned short* __restrict__ ctxb, const unsigned short* __restrict__ woT,
    float* __restrict__ out, const float* __restrict__ hs) {
  gemm_body<64>(ctxb, woT, (void*)out, hs, 2);
}

// ---------------------------------------------------------------------------
// Flash attention, round 18: 32x32x16 core, 128-thr blocks (2 waves x 32q),
// KVBLK=64, LDS 32KB -> 4 independent blocks/CU (grid 1024, XCD-clustered).
// LDS: Ks dbuf 2x8K [64 kv][128B] | Vs dbuf 2x8K V^T [64 d][128B].
// Swapped QK^T (P lane-local, col q=lane&31); PV via both-sides kv-perm;
// counted-vmcnt pipeline; setprio on MFMA clusters.
// ---------------------------------------------------------------------------
__global__ __launch_bounds__(128, 2) void k_attn(
    const unsigned short* __restrict__ q, const unsigned short* __restrict__ k,
    const unsigned short* __restrict__ vt, unsigned short* __restrict__ ctx) {
  __shared__ __align__(16) char sm[32768];
  // Ks0 @0, Ks1 @8K, Vs0 @16K, Vs1 @24K
  int t = threadIdx.x, w = t >> 6, lane = t & 63;
  int l5 = lane & 31, hi = lane >> 5, l7 = lane & 7;

  // XCD-aware decomposition: 128 consecutive-slot blocks per XCD = 4 heads
  int bid = blockIdx.x;
  int xcd = bid & 7, slot = bid >> 3;       // slot in [0,128)
  int bh = xcd * 4 + (slot >> 5);           // [0,32)
  int qt = slot & 31;                       // [0,32) q-tile of 64 rows
  int b = bh >> 4, h = bh & 15;

  const char* qB = (const char*)q + ((size_t)(b * 2048 + qt * 64) * 1024 + h * 64) * 2;
  const char* kB = (const char*)k + ((size_t)(b * 2048) * 1024 + h * 64) * 2;
  const char* vB = (const char*)vt + (size_t)bh * 64 * 4096;

  // staging geometry (128 thr; rows are 128B = 8 chunks; 16 rows per round)
  int srow = t >> 3;                               // [0,16)
  int scb  = ((t & 7) * 16) ^ ((srow & 7) << 4);   // pre-unswizzled chunk byte

  auto stageKV = [&](int buf, int it2) {
    char* Kd = sm + buf * 8192;
    char* Vd = sm + 16384 + buf * 8192;
    const char* kb2 = kB + (size_t)(it2 * 64) * 2048;
    const char* vb2 = vB + it2 * 128;
#pragma unroll
    for (int c = 0; c < 4; ++c) {
      gload16(kb2 + (size_t)(c * 16 + srow) * 2048 + scb, Kd + c * 2048 + t * 16);
      gload16(vb2 + (size_t)(c * 16 + srow) * 4096 + scb, Vd + c * 2048 + t * 16);
    }
  };

  // ---- prologue: stage Q [64 rows][128B] into Ks area, read B-frags
#pragma unroll
  for (int c = 0; c < 4; ++c)
    gload16(qB + (size_t)(c * 16 + srow) * 2048 + scb, sm + c * 2048 + t * 16);
  __syncthreads();
  s16x8 qa[4];  // B[k=d][n=q]: lane holds q=l5 (of wave's 32), d = 16s+8hi+j
#pragma unroll
  for (int s = 0; s < 4; ++s) {
    int row = w * 32 + l5;
    qa[s] = *reinterpret_cast<const s16x8*>(
        sm + row * 128 + ((32 * s + 16 * hi) ^ (l7 << 4)));
  }
  __syncthreads();  // q-frag reads done before staging overwrites Ks0
  stageKV(0, 0);
  stageKV(1, 1);

  f32x16 octx[2] = {};  // [d-tile]: C rows q=(reg&3)+8*(reg>>2)+4hi, col d=l5
  float mrun = -1e30f;
  float lsum = 0.0f;

  for (int it = 0; it < 32; ++it) {
    // ---- wait for stage(it) only; stage(it+1)'s 8 loads stay in flight
    if (it < 30) {
      asm volatile("s_waitcnt vmcnt(8)" ::: "memory");
    } else {
      asm volatile("s_waitcnt vmcnt(0)" ::: "memory");
    }
    __builtin_amdgcn_s_barrier();
    __builtin_amdgcn_sched_barrier(0);

    const char* Ks = sm + (it & 1) * 8192;
    const char* Vs = sm + 16384 + (it & 1) * 8192;

    // ---- S^T = K Q^T over 2 kv-blocks of 32
    f32x16 s2[2] = {};
    __builtin_amdgcn_s_setprio(1);
#pragma unroll
    for (int kb = 0; kb < 2; ++kb) {
#pragma unroll
      for (int s = 0; s < 4; ++s) {
        s16x8 ka = *reinterpret_cast<const s16x8*>(
            Ks + (kb * 32 + l5) * 128 + ((32 * s + 16 * hi) ^ (l7 << 4)));
        s2[kb] = __builtin_amdgcn_mfma_f32_32x32x16_bf16(ka, qa[s], s2[kb], 0, 0, 0);
      }
    }
    __builtin_amdgcn_s_setprio(0);

    // ---- online softmax (col q=l5 is lane-local; one xor-32 reduce)
    float m2 = -1e30f;
#pragma unroll
    for (int kb = 0; kb < 2; ++kb)
#pragma unroll
      for (int r = 0; r < 16; r += 2)
        m2 = f3max(m2, s2[kb][r], s2[kb][r + 1]);
    m2 = fmaxf(m2, __shfl_xor(m2, 32));
    if (__any(m2 > mrun + 8.0f)) {
      float mx = fmaxf(mrun, m2);
      float sc = EXP2(mrun - mx);
      mrun = mx;
      lsum *= sc;
#pragma unroll
      for (int r = 0; r < 16; ++r) {
        float scr = __shfl(sc, (r & 3) + 8 * (r >> 2) + 4 * hi);
        octx[0][r] *= scr;
        octx[1][r] *= scr;
      }
    }

    // ---- per kv-block: exp2 + pack into PV A-frags, then PV MFMAs
#pragma unroll
    for (int kb = 0; kb < 2; ++kb) {
      float p[16];
      float a0 = 0.0f, a1 = 0.0f;
#pragma unroll
      for (int r = 0; r < 16; r += 2) {
        p[r]     = EXP2(s2[kb][r] - mrun);
        p[r + 1] = EXP2(s2[kb][r + 1] - mrun);
        a0 += p[r]; a1 += p[r + 1];
      }
      lsum += a0 + a1;
      i32x4 pf[2];
#pragma unroll
      for (int s = 0; s < 2; ++s) {
        pf[s][0] = (int)cvtpk(p[8 * s + 0], p[8 * s + 1]);
        pf[s][1] = (int)cvtpk(p[8 * s + 2], p[8 * s + 3]);
        pf[s][2] = (int)cvtpk(p[8 * s + 4], p[8 * s + 5]);
        pf[s][3] = (int)cvtpk(p[8 * s + 6], p[8 * s + 7]);
      }
      __builtin_amdgcn_s_setprio(1);
#pragma unroll
      for (int dt = 0; dt < 2; ++dt) {
        int row = dt * 32 + l5;  // V^T row = d
        const char* vbase = Vs + row * 128;
#pragma unroll
        for (int s = 0; s < 2; ++s) {
          int coff = 64 * kb + 32 * s + 8 * hi;
          uint2 v1 = *reinterpret_cast<const uint2*>(vbase + (coff ^ (l7 << 4)));
          uint2 v2 = *reinterpret_cast<const uint2*>(vbase + ((coff + 16) ^ (l7 << 4)));
          i32x4 vv; vv[0] = (int)v1.x; vv[1] = (int)v1.y;
          vv[2] = (int)v2.x; vv[3] = (int)v2.y;
          octx[dt] = __builtin_amdgcn_mfma_f32_32x32x16_bf16(
              __builtin_bit_cast(s16x8, pf[s]),
              __builtin_bit_cast(s16x8, vv), octx[dt], 0, 0, 0);
        }
      }
      __builtin_amdgcn_s_setprio(0);
    }

    // ---- release buffers, then issue stage(it+2) into the freed buffer
    __builtin_amdgcn_s_barrier();
    __builtin_amdgcn_sched_barrier(0);
    if (it < 30) stageKV(it & 1, it + 2);
  }

  // ---- epilogue: reduce lsum across the q duplicates, normalize, store
  {
    float tot = lsum + __shfl_xor(lsum, 32);
    float inv = 1.0f / tot;
#pragma unroll
    for (int r = 0; r < 16; ++r) {
      int qrow = (r & 3) + 8 * (r >> 2) + 4 * hi;
      float invr = __shfl(inv, qrow);
      int grow = qt * 64 + w * 32 + qrow;
#pragma unroll
      for (int dt = 0; dt < 2; ++dt)
        ctx[(size_t)(b * 2048 + grow) * 1024 + h * 64 + dt * 32 + l5] =
            f2bf(octx[dt][r] * invr);
    }
  }
}

// ---------------------------------------------------------------------------
// Launch
// ---------------------------------------------------------------------------
extern "C" void kernel_launch(void* const* d_in, const int* in_sizes, int n_in,
                              void* d_out, int out_size, void* d_ws, size_t ws_size,
                              hipStream_t stream) {
  const float* hs  = (const float*)d_in[0];
  const float* kvs = (const float*)d_in[1];
  const float* wq  = (const float*)d_in[2];
  const float* wk  = (const float*)d_in[3];
  const float* wv  = (const float*)d_in[4];
  const float* wo  = (const float*)d_in[5];
  const float* nw  = (const float*)d_in[6];
  float* out = (float*)d_out;
  char* ws = (char*)d_ws;

  unsigned short* normed = (unsigned short*)(ws + (size_t)0);
  unsigned short* kvb    = (unsigned short*)(ws + ((size_t)8 << 20));
  unsigned short* wqT    = (unsigned short*)(ws + ((size_t)16 << 20));
  unsigned short* wkT    = (unsigned short*)(ws + ((size_t)18 << 20));
  unsigned short* wvT    = (unsigned short*)(ws + ((size_t)20 << 20));
  unsigned short* woT    = (unsigned short*)(ws + ((size_t)22 << 20));
  unsigned short* qb     = (unsigned short*)(ws + ((size_t)24 << 20));
  unsigned short* kb     = (unsigned short*)(ws + ((size_t)32 << 20));
  unsigned short* vTb    = (unsigned short*)(ws + ((size_t)40 << 20));
  unsigned short* ctxb   = (unsigned short*)(ws + ((size_t)48 << 20));

  k_transpose4<<<dim3(16, 16, 4), 256, 0, stream>>>(wq, wk, wv, wo, wqT, wkT, wvT, woT);
  k_prep<<<5120, 256, 0, stream>>>(hs, nw, normed, kvs, kvb);

  k_gemm_qkv<<<dim3(8, 32, 3), 256, 0, stream>>>(normed, kvb, wqT, wkT, wvT, qb, kb, vTb);

  k_attn<<<1024, 128, 0, stream>>>(qb, kb, vTb, ctxb);

  k_gemm_o<<<dim3(8, 64), 256, 0, stream>>>(ctxb, woT, out, hs);
}

// Round 19
// 132.921 us; speedup vs baseline: 1.0759x; 1.0759x over previous
//
#include <hip/hip_runtime.h>

// ---------------------------------------------------------------------------
// T5 cross-attention fused pipeline for MI355X (gfx950)  — round 19
// B=2, Q=KV=2048, D_MODEL=1024, H=16, D=64
// Round 18's attn split regressed (per-iter overhead re-sliced, occupancy
// fell). Round 19 = round-17 config (best known: 134.9us) with the weight
// transpose merged into k_prep (one fewer dispatch).
// ---------------------------------------------------------------------------

typedef __attribute__((ext_vector_type(8)))  short s16x8;   // 8 bf16 (A/B frag)
typedef __attribute__((ext_vector_type(4)))  float f32x4;
typedef __attribute__((ext_vector_type(16))) float f32x16;  // 32x32 C/D frag
typedef __attribute__((ext_vector_type(4)))  int   i32x4;

#define LOG2E 1.4426950408889634f
#define EXP2(x) __builtin_amdgcn_exp2f(x)

__device__ __forceinline__ unsigned short f2bf(float f) {
  unsigned int u = __builtin_bit_cast(unsigned int, f);
  return (unsigned short)((u + 0x7FFFu + ((u >> 16) & 1u)) >> 16);  // RNE
}

__device__ __forceinline__ unsigned cvtpk(float lo, float hi) {
  unsigned r;
  asm("v_cvt_pk_bf16_f32 %0, %1, %2" : "=v"(r) : "v"(lo), "v"(hi));
  return r;
}

__device__ __forceinline__ float f3max(float a, float b, float c) {
  return fmaxf(fmaxf(a, b), c);  // clang fuses to v_max3_f32
}

__device__ __forceinline__ void gload16(const void* g, void* l) {
  __builtin_amdgcn_global_load_lds(
      (const __attribute__((address_space(1))) unsigned int*)g,
      (__attribute__((address_space(3))) unsigned int*)l, 16, 0, 0);
}

// ---------------------------------------------------------------------------
// Fused prep, one dispatch (6144 blocks):
//   [0,4096):    RMSNorm rows (x log2e, feeds Q only)
//   [4096,5120): f32->bf16 cast of key_value_states (grid-stride)
//   [5120,6144): transpose-cast the 4 weight matrices (z = (bid-5120)>>8)
// ---------------------------------------------------------------------------
__global__ __launch_bounds__(256) void k_prep(
    const float* __restrict__ hs, const float* __restrict__ w,
    unsigned short* __restrict__ normed,
    const float* __restrict__ kvs, unsigned short* __restrict__ kvb,
    const float* __restrict__ wq, const float* __restrict__ wk,
    const float* __restrict__ wv, const float* __restrict__ wo,
    unsigned short* __restrict__ wqT, unsigned short* __restrict__ wkT,
    unsigned short* __restrict__ wvT, unsigned short* __restrict__ woT) {
  int t = threadIdx.x;
  int bid = blockIdx.x;
  if (bid < 4096) {
    int row = bid;
    float4 v = *reinterpret_cast<const float4*>(hs + (size_t)row * 1024 + t * 4);
    float s = v.x * v.x + v.y * v.y + v.z * v.z + v.w * v.w;
#pragma unroll
    for (int m = 1; m < 64; m <<= 1) s += __shfl_xor(s, m);
    __shared__ float ps[4];
    if ((t & 63) == 0) ps[t >> 6] = s;
    __syncthreads();
    float tot = ps[0] + ps[1] + ps[2] + ps[3];
    float sc = rsqrtf(tot * (1.0f / 1024.0f) + 1e-6f) * LOG2E;
    float4 wv4 = *reinterpret_cast<const float4*>(w + t * 4);
    unsigned int lo = (unsigned int)f2bf(v.x * sc * wv4.x) |
                      ((unsigned int)f2bf(v.y * sc * wv4.y) << 16);
    unsigned int hi = (unsigned int)f2bf(v.z * sc * wv4.z) |
                      ((unsigned int)f2bf(v.w * sc * wv4.w) << 16);
    uint2 pk2; pk2.x = lo; pk2.y = hi;
    *reinterpret_cast<uint2*>(normed + (size_t)row * 1024 + t * 4) = pk2;
  } else if (bid < 5120) {
    int i = (bid - 4096) * 256 + t;
    for (; i < 1048576; i += 1024 * 256) {
      float4 v = *reinterpret_cast<const float4*>(kvs + (size_t)i * 4);
      unsigned int lo = (unsigned int)f2bf(v.x) | ((unsigned int)f2bf(v.y) << 16);
      unsigned int hi = (unsigned int)f2bf(v.z) | ((unsigned int)f2bf(v.w) << 16);
      uint2 pk2; pk2.x = lo; pk2.y = hi;
      *reinterpret_cast<uint2*>(kvb + (size_t)i * 4) = pk2;
    }
  } else {
    int zz = bid - 5120;            // [0,1024)
    int z = zz >> 8;                // which matrix
    int yx = zz & 255;
    int by = yx >> 4, bx = yx & 15; // 16x16 grid of 64x64 tiles
    const float* in = (z == 0) ? wq : (z == 1) ? wk : (z == 2) ? wv : wo;
    unsigned short* out = (z == 0) ? wqT : (z == 1) ? wkT : (z == 2) ? wvT : woT;
    __shared__ float tile[64][65];
    int tx = t & 15, ty = t >> 4;
    int r0 = by * 64, c0 = bx * 64;
#pragma unroll
    for (int p = 0; p < 4; ++p) {
      int r = p * 16 + ty;
      float4 v = *reinterpret_cast<const float4*>(in + (size_t)(r0 + r) * 1024 + c0 + tx * 4);
      tile[r][tx * 4 + 0] = v.x; tile[r][tx * 4 + 1] = v.y;
      tile[r][tx * 4 + 2] = v.z; tile[r][tx * 4 + 3] = v.w;
    }
    __syncthreads();
#pragma unroll
    for (int p = 0; p < 4; ++p) {
      int c = p * 16 + ty;
      unsigned int lo = (unsigned int)f2bf(tile[tx * 4 + 0][c]) |
                        ((unsigned int)f2bf(tile[tx * 4 + 1][c]) << 16);
      unsigned int hi = (unsigned int)f2bf(tile[tx * 4 + 2][c]) |
                        ((unsigned int)f2bf(tile[tx * 4 + 3][c]) << 16);
      uint2 pk2; pk2.x = lo; pk2.y = hi;
      *reinterpret_cast<uint2*>(out + (size_t)(c0 + c) * 1024 + r0 + tx * 4) = pk2;
    }
  }
}

// ---------------------------------------------------------------------------
// GEMM body (round-17 proven): C[M,N] = A[M,K] * Bt[N,K]^T
// BK=32 (64B rows), 32KB LDS, counted-vmcnt 2-deep pipeline.
// mode 0: bf16 out; mode 1: bf16 out transposed to vT [b][h][d][2048];
// mode 2: f32 out + residual
// ---------------------------------------------------------------------------
template <int BM>
__device__ __forceinline__ void gemm_body(
    const unsigned short* __restrict__ A, const unsigned short* __restrict__ Bt,
    void* __restrict__ Cout, const float* __restrict__ resid, int mode) {
  constexpr int MF = BM / 32;              // m-frags per wave
  constexpr int AROUNDS = BM / 64;         // gload rounds per A stage (2 or 1)
  constexpr int ATILE = BM * 64;           // bytes per A buffer (8K or 4K)
  constexpr int LPS = AROUNDS + 2;         // gloads per stage (4 or 3)
  __shared__ __align__(16) char sm[2 * ATILE + 16384];
  int t = threadIdx.x;
  int bn = blockIdx.x, bm = blockIdx.y;
  int m0 = bm * BM, n0 = bn * 128;
  int lane = t & 63, w = t >> 6, lr = lane & 15, lg = lane >> 4;
  int wr = w >> 1, wc = w & 1;

  f32x4 acc[MF][4] = {};

  const char* aA = (const char*)A + ((size_t)(m0 + (t >> 2)) * 1024 + (t & 3) * 8) * 2;
  const char* aB = (const char*)Bt + ((size_t)(n0 + (t >> 2)) * 1024 + (t & 3) * 8) * 2;

  auto stage = [&](int buf, int kt) {
    int koff = kt * 64;  // bytes into the K dimension
    char* As = sm + buf * ATILE;
    char* Bs = sm + 2 * ATILE + buf * 8192;
#pragma unroll
    for (int c = 0; c < AROUNDS; ++c)
      gload16(aA + (size_t)c * 131072 + koff, As + c * 4096 + t * 16);
#pragma unroll
    for (int c = 0; c < 2; ++c)
      gload16(aB + (size_t)c * 131072 + koff, Bs + c * 4096 + t * 16);
  };

  stage(0, 0);
  stage(1, 1);
  for (int kt = 0; kt < 32; ++kt) {
    if (kt < 31) {
      asm volatile("s_waitcnt vmcnt(%0)" :: "i"(LPS) : "memory");
    } else {
      asm volatile("s_waitcnt vmcnt(0)" ::: "memory");
    }
    __builtin_amdgcn_s_barrier();
    __builtin_amdgcn_sched_barrier(0);

    const char* As = sm + (kt & 1) * ATILE;
    const char* Bs = sm + 2 * ATILE + (kt & 1) * 8192;
    s16x8 af[MF], bfr[4];
#pragma unroll
    for (int m = 0; m < MF; ++m)
      af[m] = *reinterpret_cast<const s16x8*>(
          As + (wr * (BM / 2) + m * 16 + lr) * 64 + lg * 16);
#pragma unroll
    for (int n = 0; n < 4; ++n)
      bfr[n] = *reinterpret_cast<const s16x8*>(
          Bs + (wc * 64 + n * 16 + lr) * 64 + lg * 16);
    __builtin_amdgcn_s_setprio(1);
#pragma unroll
    for (int m = 0; m < MF; ++m)
#pragma unroll
      for (int n = 0; n < 4; ++n)
        acc[m][n] = __builtin_amdgcn_mfma_f32_16x16x32_bf16(af[m], bfr[n], acc[m][n], 0, 0, 0);
    __builtin_amdgcn_s_setprio(0);

    __builtin_amdgcn_s_barrier();
    __builtin_amdgcn_sched_barrier(0);
    if (kt < 30) stage(kt & 1, kt + 2);
  }

#pragma unroll
  for (int m = 0; m < MF; ++m)
#pragma unroll
    for (int n = 0; n < 4; ++n) {
      int colg = n0 + wc * 64 + n * 16 + lr;
      int rowb = m0 + wr * (BM / 2) + m * 16 + lg * 4;
      if (mode == 0) {
        unsigned short* C = (unsigned short*)Cout;
#pragma unroll
        for (int r = 0; r < 4; ++r)
          C[(size_t)(rowb + r) * 1024 + colg] = f2bf(acc[m][n][r]);
      } else if (mode == 1) {
        int h = colg >> 6, d = colg & 63;
        int b = rowb >> 11, kv = rowb & 2047;
        unsigned short* C = (unsigned short*)Cout +
            ((size_t)((b * 16 + h) * 64 + d) * 2048 + kv);
        unsigned int lo = (unsigned int)f2bf(acc[m][n][0]) |
                          ((unsigned int)f2bf(acc[m][n][1]) << 16);
        unsigned int hi = (unsigned int)f2bf(acc[m][n][2]) |
                          ((unsigned int)f2bf(acc[m][n][3]) << 16);
        uint2 pk2; pk2.x = lo; pk2.y = hi;
        *reinterpret_cast<uint2*>(C) = pk2;
      } else {
        float* C = (float*)Cout;
#pragma unroll
        for (int r = 0; r < 4; ++r) {
          size_t idx = (size_t)(rowb + r) * 1024 + colg;
          C[idx] = resid[idx] + acc[m][n][r];
        }
      }
    }
}

__global__ __launch_bounds__(256, 4) void k_gemm_qkv(
    const unsigned short* __restrict__ normed, const unsigned short* __restrict__ kvb,
    const unsigned short* __restrict__ wqT, const unsigned short* __restrict__ wkT,
    const unsigned short* __restrict__ wvT,
    unsigned short* __restrict__ qb, unsigned short* __restrict__ kb,
    unsigned short* __restrict__ vTb) {
  int z = blockIdx.z;
  const unsigned short* A = (z == 0) ? normed : kvb;
  const unsigned short* B = (z == 0) ? wqT : (z == 1) ? wkT : wvT;
  void* C = (z == 0) ? (void*)qb : (z == 1) ? (void*)kb : (void*)vTb;
  gemm_body<128>(A, B, C, nullptr, (z == 2) ? 1 : 0);
}

__global__ __launch_bounds__(256, 4) void k_gemm_o(
    const unsigned short* __restrict__ ctxb, const unsigned short* __restrict__ woT,
    float* __restrict__ out, const float* __restrict__ hs) {
  gemm_body<64>(ctxb, woT, (void*)out, hs, 2);
}

// ---------------------------------------------------------------------------
// Flash attention (round-17 proven): 32x32x16 MFMA core.
// Grid: 512 blocks (XCD-clustered); block 256 = 4 waves; wave owns 32 q.
// LDS (64KB): Ks dbuf 2x16K [128 kv][128B] | Vs dbuf 2x16K V^T [64 d][256B].
// Swapped QK^T; in-register P via both-sides kv-permutation; counted vmcnt.
// ---------------------------------------------------------------------------
__global__ __launch_bounds__(256, 2) void k_attn(
    const unsigned short* __restrict__ q, const unsigned short* __restrict__ k,
    const unsigned short* __restrict__ vt, unsigned short* __restrict__ ctx) {
  __shared__ __align__(16) char sm[65536];
  // Ks0 @0, Ks1 @16K, Vs0 @32K, Vs1 @48K
  int t = threadIdx.x, w = t >> 6, lane = t & 63;
  int l5 = lane & 31, hi = lane >> 5, l7 = lane & 7;

  // XCD-aware decomposition: 64 consecutive-slot blocks per XCD = 4 heads
  int bid = blockIdx.x;
  int xcd = bid & 7, slot = bid >> 3;
  int bh = xcd * 4 + (slot >> 4);   // [0,32)
  int qt = slot & 15;               // [0,16)
  int b = bh >> 4, h = bh & 15;

  const char* qB = (const char*)q + ((size_t)(b * 2048 + qt * 128) * 1024 + h * 64) * 2;
  const char* kB = (const char*)k + ((size_t)(b * 2048) * 1024 + h * 64) * 2;
  const char* vB = (const char*)vt + (size_t)bh * 64 * 4096;

  // staging geometry (256 thr; pre-unswizzled sources, lane-linear dest)
  int krow = t >> 3;                               // [0,32)
  int kcb  = ((t & 7) * 16) ^ ((krow & 7) << 4);
  int vrow = t >> 4;                               // [0,16)
  int vcb  = ((t & 15) * 16) ^ ((vrow & 7) << 4);

  auto stageKV = [&](int buf, int it2) {
    char* Kd = sm + buf * 16384;
    char* Vd = sm + 32768 + buf * 16384;
    const char* kb2 = kB + (size_t)(it2 * 128) * 2048;
    const char* vb2 = vB + it2 * 256;
#pragma unroll
    for (int c = 0; c < 4; ++c) {
      gload16(kb2 + (size_t)(c * 32 + krow) * 2048 + kcb, Kd + c * 4096 + t * 16);
      gload16(vb2 + (size_t)(c * 16 + vrow) * 4096 + vcb, Vd + c * 4096 + t * 16);
    }
  };

  // ---- prologue: stage Q [128 rows][128B] into Ks0 area, read B-frags
#pragma unroll
  for (int c = 0; c < 4; ++c)
    gload16(qB + (size_t)(c * 32 + krow) * 2048 + kcb, sm + c * 4096 + t * 16);
  __syncthreads();
  s16x8 qa[4];  // B[k=d][n=q]: lane holds q=l5, d = 16s + 8hi + j
#pragma unroll
  for (int s = 0; s < 4; ++s) {
    int row = w * 32 + l5;
    qa[s] = *reinterpret_cast<const s16x8*>(
        sm + row * 128 + ((32 * s + 16 * hi) ^ (l7 << 4)));
  }
  __syncthreads();  // q-frag reads done before staging overwrites Ks0
  stageKV(0, 0);
  stageKV(1, 1);

  f32x16 octx[2] = {};  // [d-tile]: C rows q=(reg&3)+8*(reg>>2)+4hi, col d=l5
  float mrun = -1e30f;
  float lsum = 0.0f;

  for (int it = 0; it < 16; ++it) {
    // ---- wait for stage(it) only; stage(it+1)'s 8 loads stay in flight
    if (it < 14) {
      asm volatile("s_waitcnt vmcnt(8)" ::: "memory");
    } else {
      asm volatile("s_waitcnt vmcnt(0)" ::: "memory");
    }
    __builtin_amdgcn_s_barrier();
    __builtin_amdgcn_sched_barrier(0);

    const char* Ks = sm + (it & 1) * 16384;
    const char* Vs = sm + 32768 + (it & 1) * 16384;

#pragma unroll
    for (int hh = 0; hh < 2; ++hh) {  // two 64-kv halves of the 128-kv tile
      // ---- S^T = K Q^T over 2 kv-blocks of 32
      f32x16 s2[2] = {};
      __builtin_amdgcn_s_setprio(1);
#pragma unroll
      for (int kb = 0; kb < 2; ++kb) {
        int kvb = hh * 2 + kb;
#pragma unroll
        for (int s = 0; s < 4; ++s) {
          s16x8 ka = *reinterpret_cast<const s16x8*>(
              Ks + (kvb * 32 + l5) * 128 + ((32 * s + 16 * hi) ^ (l7 << 4)));
          s2[kb] = __builtin_amdgcn_mfma_f32_32x32x16_bf16(ka, qa[s], s2[kb], 0, 0, 0);
        }
      }
      __builtin_amdgcn_s_setprio(0);

      // ---- online softmax (col q=l5 is lane-local; one xor-32 reduce)
      float m2 = -1e30f;
#pragma unroll
      for (int kb = 0; kb < 2; ++kb)
#pragma unroll
        for (int r = 0; r < 16; r += 2)
          m2 = f3max(m2, s2[kb][r], s2[kb][r + 1]);
      m2 = fmaxf(m2, __shfl_xor(m2, 32));
      if (__any(m2 > mrun + 8.0f)) {
        float mx = fmaxf(mrun, m2);
        float sc = EXP2(mrun - mx);
        mrun = mx;
        lsum *= sc;
#pragma unroll
        for (int r = 0; r < 16; ++r) {
          float scr = __shfl(sc, (r & 3) + 8 * (r >> 2) + 4 * hi);
          octx[0][r] *= scr;
          octx[1][r] *= scr;
        }
      }

      // ---- per kv-block: exp2 + pack into PV A-frags, then PV MFMAs
#pragma unroll
      for (int kb = 0; kb < 2; ++kb) {
        int kvb = hh * 2 + kb;
        float p[16];
        float a0 = 0.0f, a1 = 0.0f;
#pragma unroll
        for (int r = 0; r < 16; r += 2) {
          p[r]     = EXP2(s2[kb][r] - mrun);
          p[r + 1] = EXP2(s2[kb][r + 1] - mrun);
          a0 += p[r]; a1 += p[r + 1];
        }
        lsum += a0 + a1;
        i32x4 pf[2];
#pragma unroll
        for (int s = 0; s < 2; ++s) {
          pf[s][0] = (int)cvtpk(p[8 * s + 0], p[8 * s + 1]);
          pf[s][1] = (int)cvtpk(p[8 * s + 2], p[8 * s + 3]);
          pf[s][2] = (int)cvtpk(p[8 * s + 4], p[8 * s + 5]);
          pf[s][3] = (int)cvtpk(p[8 * s + 6], p[8 * s + 7]);
        }
        __builtin_amdgcn_s_setprio(1);
#pragma unroll
        for (int dt = 0; dt < 2; ++dt) {
          int row = dt * 32 + l5;  // V^T row = d
          const char* vbase = Vs + row * 256;
#pragma unroll
          for (int s = 0; s < 2; ++s) {
            int coff = 64 * kvb + 32 * s + 8 * hi;
            uint2 v1 = *reinterpret_cast<const uint2*>(vbase + (coff ^ (l7 << 4)));
            uint2 v2 = *reinterpret_cast<const uint2*>(vbase + ((coff + 16) ^ (l7 << 4)));
            i32x4 vv; vv[0] = (int)v1.x; vv[1] = (int)v1.y;
            vv[2] = (int)v2.x; vv[3] = (int)v2.y;
            octx[dt] = __builtin_amdgcn_mfma_f32_32x32x16_bf16(
                __builtin_bit_cast(s16x8, pf[s]),
                __builtin_bit_cast(s16x8, vv), octx[dt], 0, 0, 0);
          }
        }
        __builtin_amdgcn_s_setprio(0);
      }
    }

    // ---- release buffers, then issue stage(it+2) into the freed buffer
    __builtin_amdgcn_s_barrier();
    __builtin_amdgcn_sched_barrier(0);
    if (it < 14) stageKV(it & 1, it + 2);
  }

  // ---- epilogue: reduce lsum across the q duplicates, normalize, store
  {
    float tot = lsum + __shfl_xor(lsum, 32);
    float inv = 1.0f / tot;
#pragma unroll
    for (int r = 0; r < 16; ++r) {
      int qrow = (r & 3) + 8 * (r >> 2) + 4 * hi;
      float invr = __shfl(inv, qrow);
      int grow = qt * 128 + w * 32 + qrow;
#pragma unroll
      for (int dt = 0; dt < 2; ++dt)
        ctx[(size_t)(b * 2048 + grow) * 1024 + h * 64 + dt * 32 + l5] =
            f2bf(octx[dt][r] * invr);
    }
  }
}

// ---------------------------------------------------------------------------
// Launch
// ---------------------------------------------------------------------------
extern "C" void kernel_launch(void* const* d_in, const int* in_sizes, int n_in,
                              void* d_out, int out_size, void* d_ws, size_t ws_size,
                              hipStream_t stream) {
  const float* hs  = (const float*)d_in[0];
  const float* kvs = (const float*)d_in[1];
  const float* wq  = (const float*)d_in[2];
  const float* wk  = (const float*)d_in[3];
  const float* wv  = (const float*)d_in[4];
  const float* wo  = (const float*)d_in[5];
  const float* nw  = (const float*)d_in[6];
  float* out = (float*)d_out;
  char* ws = (char*)d_ws;

  unsigned short* normed = (unsigned short*)(ws + (size_t)0);
  unsigned short* kvb    = (unsigned short*)(ws + ((size_t)8 << 20));
  unsigned short* wqT    = (unsigned short*)(ws + ((size_t)16 << 20));
  unsigned short* wkT    = (unsigned short*)(ws + ((size_t)18 << 20));
  unsigned short* wvT    = (unsigned short*)(ws + ((size_t)20 << 20));
  unsigned short* woT    = (unsigned short*)(ws + ((size_t)22 << 20));
  unsigned short* qb     = (unsigned short*)(ws + ((size_t)24 << 20));
  unsigned short* kb     = (unsigned short*)(ws + ((size_t)32 << 20));
  unsigned short* vTb    = (unsigned short*)(ws + ((size_t)40 << 20));
  unsigned short* ctxb   = (unsigned short*)(ws + ((size_t)48 << 20));

  k_prep<<<6144, 256, 0, stream>>>(hs, nw, normed, kvs, kvb,
                                   wq, wk, wv, wo, wqT, wkT, wvT, woT);

  k_gemm_qkv<<<dim3(8, 32, 3), 256, 0, stream>>>(normed, kvb, wqT, wkT, wvT, qb, kb, vTb);

  k_attn<<<512, 256, 0, stream>>>(qb, kb, vTb, ctxb);

  k_gemm_o<<<dim3(8, 64), 256, 0, stream>>>(ctxb, woT, out, hs);
}

// Round 20
// 130.570 us; speedup vs baseline: 1.0953x; 1.0180x over previous
//
#include <hip/hip_runtime.h>

// ---------------------------------------------------------------------------
// T5 cross-attention fused pipeline for MI355X (gfx950)  — round 20
// B=2, Q=KV=2048, D_MODEL=1024, H=16, D=64
// attn: T15-style dependency break — QKT for ALL 4 kv-blocks first (one
// softmax-max update per 128-kv tile), then per-block {exp/pack || PV} so
// PV MFMAs overlap the next block's exp VALU. Rest = round-19 (132.9us).
// Risk: s2[4] f32x16 adds ~64 VGPR (est ~200 total, no spill expected).
// ---------------------------------------------------------------------------

typedef __attribute__((ext_vector_type(8)))  short s16x8;   // 8 bf16 (A/B frag)
typedef __attribute__((ext_vector_type(4)))  float f32x4;
typedef __attribute__((ext_vector_type(16))) float f32x16;  // 32x32 C/D frag
typedef __attribute__((ext_vector_type(4)))  int   i32x4;

#define LOG2E 1.4426950408889634f
#define EXP2(x) __builtin_amdgcn_exp2f(x)

__device__ __forceinline__ unsigned short f2bf(float f) {
  unsigned int u = __builtin_bit_cast(unsigned int, f);
  return (unsigned short)((u + 0x7FFFu + ((u >> 16) & 1u)) >> 16);  // RNE
}

__device__ __forceinline__ unsigned cvtpk(float lo, float hi) {
  unsigned r;
  asm("v_cvt_pk_bf16_f32 %0, %1, %2" : "=v"(r) : "v"(lo), "v"(hi));
  return r;
}

__device__ __forceinline__ float f3max(float a, float b, float c) {
  return fmaxf(fmaxf(a, b), c);  // clang fuses to v_max3_f32
}

__device__ __forceinline__ void gload16(const void* g, void* l) {
  __builtin_amdgcn_global_load_lds(
      (const __attribute__((address_space(1))) unsigned int*)g,
      (__attribute__((address_space(3))) unsigned int*)l, 16, 0, 0);
}

// ---------------------------------------------------------------------------
// Fused prep, one dispatch (6144 blocks):
//   [0,4096):    RMSNorm rows (x log2e, feeds Q only)
//   [4096,5120): f32->bf16 cast of key_value_states (grid-stride)
//   [5120,6144): transpose-cast the 4 weight matrices (z = (bid-5120)>>8)
// ---------------------------------------------------------------------------
__global__ __launch_bounds__(256) void k_prep(
    const float* __restrict__ hs, const float* __restrict__ w,
    unsigned short* __restrict__ normed,
    const float* __restrict__ kvs, unsigned short* __restrict__ kvb,
    const float* __restrict__ wq, const float* __restrict__ wk,
    const float* __restrict__ wv, const float* __restrict__ wo,
    unsigned short* __restrict__ wqT, unsigned short* __restrict__ wkT,
    unsigned short* __restrict__ wvT, unsigned short* __restrict__ woT) {
  int t = threadIdx.x;
  int bid = blockIdx.x;
  if (bid < 4096) {
    int row = bid;
    float4 v = *reinterpret_cast<const float4*>(hs + (size_t)row * 1024 + t * 4);
    float s = v.x * v.x + v.y * v.y + v.z * v.z + v.w * v.w;
#pragma unroll
    for (int m = 1; m < 64; m <<= 1) s += __shfl_xor(s, m);
    __shared__ float ps[4];
    if ((t & 63) == 0) ps[t >> 6] = s;
    __syncthreads();
    float tot = ps[0] + ps[1] + ps[2] + ps[3];
    float sc = rsqrtf(tot * (1.0f / 1024.0f) + 1e-6f) * LOG2E;
    float4 wv4 = *reinterpret_cast<const float4*>(w + t * 4);
    unsigned int lo = (unsigned int)f2bf(v.x * sc * wv4.x) |
                      ((unsigned int)f2bf(v.y * sc * wv4.y) << 16);
    unsigned int hi = (unsigned int)f2bf(v.z * sc * wv4.z) |
                      ((unsigned int)f2bf(v.w * sc * wv4.w) << 16);
    uint2 pk2; pk2.x = lo; pk2.y = hi;
    *reinterpret_cast<uint2*>(normed + (size_t)row * 1024 + t * 4) = pk2;
  } else if (bid < 5120) {
    int i = (bid - 4096) * 256 + t;
    for (; i < 1048576; i += 1024 * 256) {
      float4 v = *reinterpret_cast<const float4*>(kvs + (size_t)i * 4);
      unsigned int lo = (unsigned int)f2bf(v.x) | ((unsigned int)f2bf(v.y) << 16);
      unsigned int hi = (unsigned int)f2bf(v.z) | ((unsigned int)f2bf(v.w) << 16);
      uint2 pk2; pk2.x = lo; pk2.y = hi;
      *reinterpret_cast<uint2*>(kvb + (size_t)i * 4) = pk2;
    }
  } else {
    int zz = bid - 5120;            // [0,1024)
    int z = zz >> 8;                // which matrix
    int yx = zz & 255;
    int by = yx >> 4, bx = yx & 15; // 16x16 grid of 64x64 tiles
    const float* in = (z == 0) ? wq : (z == 1) ? wk : (z == 2) ? wv : wo;
    unsigned short* out = (z == 0) ? wqT : (z == 1) ? wkT : (z == 2) ? wvT : woT;
    __shared__ float tile[64][65];
    int tx = t & 15, ty = t >> 4;
    int r0 = by * 64, c0 = bx * 64;
#pragma unroll
    for (int p = 0; p < 4; ++p) {
      int r = p * 16 + ty;
      float4 v = *reinterpret_cast<const float4*>(in + (size_t)(r0 + r) * 1024 + c0 + tx * 4);
      tile[r][tx * 4 + 0] = v.x; tile[r][tx * 4 + 1] = v.y;
      tile[r][tx * 4 + 2] = v.z; tile[r][tx * 4 + 3] = v.w;
    }
    __syncthreads();
#pragma unroll
    for (int p = 0; p < 4; ++p) {
      int c = p * 16 + ty;
      unsigned int lo = (unsigned int)f2bf(tile[tx * 4 + 0][c]) |
                        ((unsigned int)f2bf(tile[tx * 4 + 1][c]) << 16);
      unsigned int hi = (unsigned int)f2bf(tile[tx * 4 + 2][c]) |
                        ((unsigned int)f2bf(tile[tx * 4 + 3][c]) << 16);
      uint2 pk2; pk2.x = lo; pk2.y = hi;
      *reinterpret_cast<uint2*>(out + (size_t)(c0 + c) * 1024 + r0 + tx * 4) = pk2;
    }
  }
}

// ---------------------------------------------------------------------------
// GEMM body (round-17 proven): C[M,N] = A[M,K] * Bt[N,K]^T
// BK=32 (64B rows), 32KB LDS, counted-vmcnt 2-deep pipeline.
// mode 0: bf16 out; mode 1: bf16 out transposed to vT [b][h][d][2048];
// mode 2: f32 out + residual
// ---------------------------------------------------------------------------
template <int BM>
__device__ __forceinline__ void gemm_body(
    const unsigned short* __restrict__ A, const unsigned short* __restrict__ Bt,
    void* __restrict__ Cout, const float* __restrict__ resid, int mode) {
  constexpr int MF = BM / 32;              // m-frags per wave
  constexpr int AROUNDS = BM / 64;         // gload rounds per A stage (2 or 1)
  constexpr int ATILE = BM * 64;           // bytes per A buffer (8K or 4K)
  constexpr int LPS = AROUNDS + 2;         // gloads per stage (4 or 3)
  __shared__ __align__(16) char sm[2 * ATILE + 16384];
  int t = threadIdx.x;
  int bn = blockIdx.x, bm = blockIdx.y;
  int m0 = bm * BM, n0 = bn * 128;
  int lane = t & 63, w = t >> 6, lr = lane & 15, lg = lane >> 4;
  int wr = w >> 1, wc = w & 1;

  f32x4 acc[MF][4] = {};

  const char* aA = (const char*)A + ((size_t)(m0 + (t >> 2)) * 1024 + (t & 3) * 8) * 2;
  const char* aB = (const char*)Bt + ((size_t)(n0 + (t >> 2)) * 1024 + (t & 3) * 8) * 2;

  auto stage = [&](int buf, int kt) {
    int koff = kt * 64;  // bytes into the K dimension
    char* As = sm + buf * ATILE;
    char* Bs = sm + 2 * ATILE + buf * 8192;
#pragma unroll
    for (int c = 0; c < AROUNDS; ++c)
      gload16(aA + (size_t)c * 131072 + koff, As + c * 4096 + t * 16);
#pragma unroll
    for (int c = 0; c < 2; ++c)
      gload16(aB + (size_t)c * 131072 + koff, Bs + c * 4096 + t * 16);
  };

  stage(0, 0);
  stage(1, 1);
  for (int kt = 0; kt < 32; ++kt) {
    if (kt < 31) {
      asm volatile("s_waitcnt vmcnt(%0)" :: "i"(LPS) : "memory");
    } else {
      asm volatile("s_waitcnt vmcnt(0)" ::: "memory");
    }
    __builtin_amdgcn_s_barrier();
    __builtin_amdgcn_sched_barrier(0);

    const char* As = sm + (kt & 1) * ATILE;
    const char* Bs = sm + 2 * ATILE + (kt & 1) * 8192;
    s16x8 af[MF], bfr[4];
#pragma unroll
    for (int m = 0; m < MF; ++m)
      af[m] = *reinterpret_cast<const s16x8*>(
          As + (wr * (BM / 2) + m * 16 + lr) * 64 + lg * 16);
#pragma unroll
    for (int n = 0; n < 4; ++n)
      bfr[n] = *reinterpret_cast<const s16x8*>(
          Bs + (wc * 64 + n * 16 + lr) * 64 + lg * 16);
    __builtin_amdgcn_s_setprio(1);
#pragma unroll
    for (int m = 0; m < MF; ++m)
#pragma unroll
      for (int n = 0; n < 4; ++n)
        acc[m][n] = __builtin_amdgcn_mfma_f32_16x16x32_bf16(af[m], bfr[n], acc[m][n], 0, 0, 0);
    __builtin_amdgcn_s_setprio(0);

    __builtin_amdgcn_s_barrier();
    __builtin_amdgcn_sched_barrier(0);
    if (kt < 30) stage(kt & 1, kt + 2);
  }

#pragma unroll
  for (int m = 0; m < MF; ++m)
#pragma unroll
    for (int n = 0; n < 4; ++n) {
      int colg = n0 + wc * 64 + n * 16 + lr;
      int rowb = m0 + wr * (BM / 2) + m * 16 + lg * 4;
      if (mode == 0) {
        unsigned short* C = (unsigned short*)Cout;
#pragma unroll
        for (int r = 0; r < 4; ++r)
          C[(size_t)(rowb + r) * 1024 + colg] = f2bf(acc[m][n][r]);
      } else if (mode == 1) {
        int h = colg >> 6, d = colg & 63;
        int b = rowb >> 11, kv = rowb & 2047;
        unsigned short* C = (unsigned short*)Cout +
            ((size_t)((b * 16 + h) * 64 + d) * 2048 + kv);
        unsigned int lo = (unsigned int)f2bf(acc[m][n][0]) |
                          ((unsigned int)f2bf(acc[m][n][1]) << 16);
        unsigned int hi = (unsigned int)f2bf(acc[m][n][2]) |
                          ((unsigned int)f2bf(acc[m][n][3]) << 16);
        uint2 pk2; pk2.x = lo; pk2.y = hi;
        *reinterpret_cast<uint2*>(C) = pk2;
      } else {
        float* C = (float*)Cout;
#pragma unroll
        for (int r = 0; r < 4; ++r) {
          size_t idx = (size_t)(rowb + r) * 1024 + colg;
          C[idx] = resid[idx] + acc[m][n][r];
        }
      }
    }
}

__global__ __launch_bounds__(256, 4) void k_gemm_qkv(
    const unsigned short* __restrict__ normed, const unsigned short* __restrict__ kvb,
    const unsigned short* __restrict__ wqT, const unsigned short* __restrict__ wkT,
    const unsigned short* __restrict__ wvT,
    unsigned short* __restrict__ qb, unsigned short* __restrict__ kb,
    unsigned short* __restrict__ vTb) {
  int z = blockIdx.z;
  const unsigned short* A = (z == 0) ? normed : kvb;
  const unsigned short* B = (z == 0) ? wqT : (z == 1) ? wkT : wvT;
  void* C = (z == 0) ? (void*)qb : (z == 1) ? (void*)kb : (void*)vTb;
  gemm_body<128>(A, B, C, nullptr, (z == 2) ? 1 : 0);
}

__global__ __launch_bounds__(256, 4) void k_gemm_o(
    const unsigned short* __restrict__ ctxb, const unsigned short* __restrict__ woT,
    float* __restrict__ out, const float* __restrict__ hs) {
  gemm_body<64>(ctxb, woT, (void*)out, hs, 2);
}

// ---------------------------------------------------------------------------
// Flash attention, round 20: 32x32x16 core with T15 dependency break.
// Grid: 512 blocks (XCD-clustered); block 256 = 4 waves; wave owns 32 q.
// LDS (64KB): Ks dbuf 2x16K [128 kv][128B] | Vs dbuf 2x16K V^T [64 d][256B].
// Per iter: QKT for ALL 4 kv-blocks -> ONE softmax-max update -> per-block
// {exp/pack || PV} so PV MFMAs overlap next block's exp VALU.
// ---------------------------------------------------------------------------
__global__ __launch_bounds__(256, 2) void k_attn(
    const unsigned short* __restrict__ q, const unsigned short* __restrict__ k,
    const unsigned short* __restrict__ vt, unsigned short* __restrict__ ctx) {
  __shared__ __align__(16) char sm[65536];
  // Ks0 @0, Ks1 @16K, Vs0 @32K, Vs1 @48K
  int t = threadIdx.x, w = t >> 6, lane = t & 63;
  int l5 = lane & 31, hi = lane >> 5, l7 = lane & 7;

  // XCD-aware decomposition: 64 consecutive-slot blocks per XCD = 4 heads
  int bid = blockIdx.x;
  int xcd = bid & 7, slot = bid >> 3;
  int bh = xcd * 4 + (slot >> 4);   // [0,32)
  int qt = slot & 15;               // [0,16)
  int b = bh >> 4, h = bh & 15;

  const char* qB = (const char*)q + ((size_t)(b * 2048 + qt * 128) * 1024 + h * 64) * 2;
  const char* kB = (const char*)k + ((size_t)(b * 2048) * 1024 + h * 64) * 2;
  const char* vB = (const char*)vt + (size_t)bh * 64 * 4096;

  // staging geometry (256 thr; pre-unswizzled sources, lane-linear dest)
  int krow = t >> 3;                               // [0,32)
  int kcb  = ((t & 7) * 16) ^ ((krow & 7) << 4);
  int vrow = t >> 4;                               // [0,16)
  int vcb  = ((t & 15) * 16) ^ ((vrow & 7) << 4);

  auto stageKV = [&](int buf, int it2) {
    char* Kd = sm + buf * 16384;
    char* Vd = sm + 32768 + buf * 16384;
    const char* kb2 = kB + (size_t)(it2 * 128) * 2048;
    const char* vb2 = vB + it2 * 256;
#pragma unroll
    for (int c = 0; c < 4; ++c) {
      gload16(kb2 + (size_t)(c * 32 + krow) * 2048 + kcb, Kd + c * 4096 + t * 16);
      gload16(vb2 + (size_t)(c * 16 + vrow) * 4096 + vcb, Vd + c * 4096 + t * 16);
    }
  };

  // ---- prologue: stage Q [128 rows][128B] into Ks0 area, read B-frags
#pragma unroll
  for (int c = 0; c < 4; ++c)
    gload16(qB + (size_t)(c * 32 + krow) * 2048 + kcb, sm + c * 4096 + t * 16);
  __syncthreads();
  s16x8 qa[4];  // B[k=d][n=q]: lane holds q=l5, d = 16s + 8hi + j
#pragma unroll
  for (int s = 0; s < 4; ++s) {
    int row = w * 32 + l5;
    qa[s] = *reinterpret_cast<const s16x8*>(
        sm + row * 128 + ((32 * s + 16 * hi) ^ (l7 << 4)));
  }
  __syncthreads();  // q-frag reads done before staging overwrites Ks0
  stageKV(0, 0);
  stageKV(1, 1);

  f32x16 octx[2] = {};  // [d-tile]: C rows q=(reg&3)+8*(reg>>2)+4hi, col d=l5
  float mrun = -1e30f;
  float lsum = 0.0f;

  for (int it = 0; it < 16; ++it) {
    // ---- wait for stage(it) only; stage(it+1)'s 8 loads stay in flight
    if (it < 14) {
      asm volatile("s_waitcnt vmcnt(8)" ::: "memory");
    } else {
      asm volatile("s_waitcnt vmcnt(0)" ::: "memory");
    }
    __builtin_amdgcn_s_barrier();
    __builtin_amdgcn_sched_barrier(0);

    const char* Ks = sm + (it & 1) * 16384;
    const char* Vs = sm + 32768 + (it & 1) * 16384;

    // ---- S^T = K Q^T for ALL 4 kv-blocks of 32 (one MFMA cluster)
    f32x16 s2[4] = {};
    __builtin_amdgcn_s_setprio(1);
#pragma unroll
    for (int kvb = 0; kvb < 4; ++kvb) {
#pragma unroll
      for (int s = 0; s < 4; ++s) {
        s16x8 ka = *reinterpret_cast<const s16x8*>(
            Ks + (kvb * 32 + l5) * 128 + ((32 * s + 16 * hi) ^ (l7 << 4)));
        s2[kvb] = __builtin_amdgcn_mfma_f32_32x32x16_bf16(ka, qa[s], s2[kvb], 0, 0, 0);
      }
    }
    __builtin_amdgcn_s_setprio(0);

    // ---- ONE softmax-max update per 128-kv tile
    float m2 = -1e30f;
#pragma unroll
    for (int kvb = 0; kvb < 4; ++kvb)
#pragma unroll
      for (int r = 0; r < 16; r += 2)
        m2 = f3max(m2, s2[kvb][r], s2[kvb][r + 1]);
    m2 = fmaxf(m2, __shfl_xor(m2, 32));
    if (__any(m2 > mrun + 8.0f)) {
      float mx = fmaxf(mrun, m2);
      float sc = EXP2(mrun - mx);
      mrun = mx;
      lsum *= sc;
#pragma unroll
      for (int r = 0; r < 16; ++r) {
        float scr = __shfl(sc, (r & 3) + 8 * (r >> 2) + 4 * hi);
        octx[0][r] *= scr;
        octx[1][r] *= scr;
      }
    }

    // ---- per kv-block: exp2 + pack, then PV (PV(i) overlaps exp(i+1))
#pragma unroll
    for (int kvb = 0; kvb < 4; ++kvb) {
      float p[16];
      float a0 = 0.0f, a1 = 0.0f;
#pragma unroll
      for (int r = 0; r < 16; r += 2) {
        p[r]     = EXP2(s2[kvb][r] - mrun);
        p[r + 1] = EXP2(s2[kvb][r + 1] - mrun);
        a0 += p[r]; a1 += p[r + 1];
      }
      lsum += a0 + a1;
      i32x4 pf[2];
#pragma unroll
      for (int s = 0; s < 2; ++s) {
        pf[s][0] = (int)cvtpk(p[8 * s + 0], p[8 * s + 1]);
        pf[s][1] = (int)cvtpk(p[8 * s + 2], p[8 * s + 3]);
        pf[s][2] = (int)cvtpk(p[8 * s + 4], p[8 * s + 5]);
        pf[s][3] = (int)cvtpk(p[8 * s + 6], p[8 * s + 7]);
      }
      __builtin_amdgcn_s_setprio(1);
#pragma unroll
      for (int dt = 0; dt < 2; ++dt) {
        int row = dt * 32 + l5;  // V^T row = d
        const char* vbase = Vs + row * 256;
#pragma unroll
        for (int s = 0; s < 2; ++s) {
          int coff = 64 * kvb + 32 * s + 8 * hi;
          uint2 v1 = *reinterpret_cast<const uint2*>(vbase + (coff ^ (l7 << 4)));
          uint2 v2 = *reinterpret_cast<const uint2*>(vbase + ((coff + 16) ^ (l7 << 4)));
          i32x4 vv; vv[0] = (int)v1.x; vv[1] = (int)v1.y;
          vv[2] = (int)v2.x; vv[3] = (int)v2.y;
          octx[dt] = __builtin_amdgcn_mfma_f32_32x32x16_bf16(
              __builtin_bit_cast(s16x8, pf[s]),
              __builtin_bit_cast(s16x8, vv), octx[dt], 0, 0, 0);
        }
      }
      __builtin_amdgcn_s_setprio(0);
    }

    // ---- release buffers, then issue stage(it+2) into the freed buffer
    __builtin_amdgcn_s_barrier();
    __builtin_amdgcn_sched_barrier(0);
    if (it < 14) stageKV(it & 1, it + 2);
  }

  // ---- epilogue: reduce lsum across the q duplicates, normalize, store
  {
    float tot = lsum + __shfl_xor(lsum, 32);
    float inv = 1.0f / tot;
#pragma unroll
    for (int r = 0; r < 16; ++r) {
      int qrow = (r & 3) + 8 * (r >> 2) + 4 * hi;
      float invr = __shfl(inv, qrow);
      int grow = qt * 128 + w * 32 + qrow;
#pragma unroll
      for (int dt = 0; dt < 2; ++dt)
        ctx[(size_t)(b * 2048 + grow) * 1024 + h * 64 + dt * 32 + l5] =
            f2bf(octx[dt][r] * invr);
    }
  }
}

// ---------------------------------------------------------------------------
// Launch
// ---------------------------------------------------------------------------
extern "C" void kernel_launch(void* const* d_in, const int* in_sizes, int n_in,
                              void* d_out, int out_size, void* d_ws, size_t ws_size,
                              hipStream_t stream) {
  const float* hs  = (const float*)d_in[0];
  const float* kvs = (const float*)d_in[1];
  const float* wq  = (const float*)d_in[2];
  const float* wk  = (const float*)d_in[3];
  const float* wv  = (const float*)d_in[4];
  const float* wo  = (const float*)d_in[5];
  const float* nw  = (const float*)d_in[6];
  float* out = (float*)d_out;
  char* ws = (char*)d_ws;

  unsigned short* normed = (unsigned short*)(ws + (size_t)0);
  unsigned short* kvb    = (unsigned short*)(ws + ((size_t)8 << 20));
  unsigned short* wqT    = (unsigned short*)(ws + ((size_t)16 << 20));
  unsigned short* wkT    = (unsigned short*)(ws + ((size_t)18 << 20));
  unsigned short* wvT    = (unsigned short*)(ws + ((size_t)20 << 20));
  unsigned short* woT    = (unsigned short*)(ws + ((size_t)22 << 20));
  unsigned short* qb     = (unsigned short*)(ws + ((size_t)24 << 20));
  unsigned short* kb     = (unsigned short*)(ws + ((size_t)32 << 20));
  unsigned short* vTb    = (unsigned short*)(ws + ((size_t)40 << 20));
  unsigned short* ctxb   = (unsigned short*)(ws + ((size_t)48 << 20));

  k_prep<<<6144, 256, 0, stream>>>(hs, nw, normed, kvs, kvb,
                                   wq, wk, wv, wo, wqT, wkT, wvT, woT);

  k_gemm_qkv<<<dim3(8, 32, 3), 256, 0, stream>>>(normed, kvb, wqT, wkT, wvT, qb, kb, vTb);

  k_attn<<<512, 256, 0, stream>>>(qb, kb, vTb, ctxb);

  k_gemm_o<<<dim3(8, 64), 256, 0, stream>>>(ctxb, woT, out, hs);
}